// Round 1
// baseline (608.446 us; speedup 1.0000x reference)
//
#include <hip/hip_runtime.h>
#include <math.h>

// Problem constants
constexpr int Bn  = 16;
constexpr int Cn  = 256;
constexpr int Mn  = 16384;  // 128*128
constexpr int ICn = 32;

// ---- workspace layout (in floats) ----
// gx  : [B][32][M]   g-projection (g_w@x + g_b)
// wt  : [256][64]    transposed fused weights: wt[k][i] = (i<32 ? g_w[i][k] : theta_w[i-32][k])
// wct : [B][32][256] folded output weights: wct[b][j][c] = sum_i w_w[c][i]*attn[b][i][j]
// tt  : [B][32][32]  accumulator for t@t^T  (atomicAdd)
// mu  : [B][32]      accumulator for sum_m t (atomicAdd)
constexpr size_t OFF_GX  = 0;
constexpr size_t OFF_WT  = OFF_GX  + (size_t)Bn * ICn * Mn;   // 8388608
constexpr size_t OFF_WCT = OFF_WT  + (size_t)Cn * 64;          // +16384
constexpr size_t OFF_TT  = OFF_WCT + (size_t)Bn * ICn * Cn;    // +131072
constexpr size_t OFF_MU  = OFF_TT  + (size_t)Bn * ICn * ICn;   // +16384

// ---------------- K0: weight transpose ----------------
__global__ void k0_transpose_w(const float* __restrict__ g_w,
                               const float* __restrict__ theta_w,
                               float* __restrict__ wt) {
    int idx = blockIdx.x * 256 + threadIdx.x;  // 16384 total
    int k = idx >> 6;
    int i = idx & 63;
    float v = (i < 32) ? g_w[i * Cn + k] : theta_w[(i - 32) * Cn + k];
    wt[idx] = v;
}

// ---------------- K1: projections + covariance stats ----------------
// Grid (64, B), 256 threads. Each block: 256 pixels of one batch.
// Thread = (mq = tx&63 -> pixel quad, ig = tx>>6 -> 16-row i-group).
// Inner loop: coalesced float4 x load + 64 FMA with SGPR-resident weights.
__global__ __launch_bounds__(256, 4) void k1_proj(
    const float* __restrict__ x,
    const float* __restrict__ wt,
    const float* __restrict__ g_b,
    const float* __restrict__ theta_b,
    float* __restrict__ gx,
    float* __restrict__ tt,
    float* __restrict__ mu)
{
    __shared__ float ts[32][260];    // theta tile, padded stride
    __shared__ float sig[ICn * ICn]; // block-local sigma partial

    const int tx = threadIdx.x;
    const int b  = blockIdx.y;
    const int m0 = blockIdx.x * 256;
    const int mq = tx & 63;
    const int ig = tx >> 6;                         // 0..3 (wave-uniform)
    const int igu = __builtin_amdgcn_readfirstlane(ig);
    const int m  = m0 + mq * 4;

    for (int p = tx; p < ICn * ICn; p += 256) sig[p] = 0.f;

    float acc[16][4];
    #pragma unroll
    for (int i = 0; i < 16; ++i)
        acc[i][0] = acc[i][1] = acc[i][2] = acc[i][3] = 0.f;

    const float4* __restrict__ xq =
        (const float4*)(x + (size_t)b * Cn * Mn + m);
    const float* __restrict__ wtg = wt + igu * 16;

    #pragma unroll 4
    for (int k = 0; k < Cn; ++k) {
        float4 xv = xq[(size_t)k * (Mn / 4)];
        #pragma unroll
        for (int i = 0; i < 16; ++i) {
            float w = wtg[k * 64 + i];   // wave-uniform -> s_load
            acc[i][0] += w * xv.x;
            acc[i][1] += w * xv.y;
            acc[i][2] += w * xv.z;
            acc[i][3] += w * xv.w;
        }
    }

    if (ig < 2) {
        // g rows 0..31 -> global write (+bias)
        #pragma unroll
        for (int i = 0; i < 16; ++i) {
            int gi = ig * 16 + i;
            float bb = g_b[gi];
            float4 v = make_float4(acc[i][0] + bb, acc[i][1] + bb,
                                   acc[i][2] + bb, acc[i][3] + bb);
            *(float4*)(gx + ((size_t)b * ICn + gi) * Mn + m) = v;
        }
    } else {
        // theta rows 0..31 -> LDS (+bias)
        #pragma unroll
        for (int i = 0; i < 16; ++i) {
            int ti = (ig - 2) * 16 + i;
            float bb = theta_b[ti];
            float4 v = make_float4(acc[i][0] + bb, acc[i][1] + bb,
                                   acc[i][2] + bb, acc[i][3] + bb);
            *(float4*)&ts[ti][mq * 4] = v;
        }
    }
    __syncthreads();

    // ---- block-local t t^T over 256 pixels ----
    // thread -> (i0,j0) 4x4 tile of 32x32, msub = quarter of pixels
    {
        const int i0 = (tx & 7) * 4;
        const int j0 = ((tx >> 3) & 7) * 4;
        const int ms = (tx >> 6) * 64;
        float s2[4][4] = {};
        for (int mm = 0; mm < 64; mm += 4) {
            float4 av[4], bv[4];
            #pragma unroll
            for (int a = 0; a < 4; ++a) av[a] = *(const float4*)&ts[i0 + a][ms + mm];
            #pragma unroll
            for (int c = 0; c < 4; ++c) bv[c] = *(const float4*)&ts[j0 + c][ms + mm];
            #pragma unroll
            for (int a = 0; a < 4; ++a)
                #pragma unroll
                for (int c = 0; c < 4; ++c)
                    s2[a][c] += av[a].x * bv[c].x + av[a].y * bv[c].y +
                                av[a].z * bv[c].z + av[a].w * bv[c].w;
        }
        #pragma unroll
        for (int a = 0; a < 4; ++a)
            #pragma unroll
            for (int c = 0; c < 4; ++c)
                atomicAdd(&sig[(i0 + a) * 32 + (j0 + c)], s2[a][c]);
    }

    // ---- mu partials ----
    {
        int i = tx & 31, seg = tx >> 5;
        const float* r = &ts[i][seg * 32];
        float s = 0.f;
        #pragma unroll
        for (int q = 0; q < 32; q += 4) {
            float4 v = *(const float4*)(r + q);
            s += (v.x + v.y) + (v.z + v.w);
        }
        atomicAdd(&mu[b * ICn + i], s);
    }

    __syncthreads();
    for (int p = tx; p < ICn * ICn; p += 256)
        atomicAdd(&tt[b * ICn * ICn + p], sig[p]);
}

// ---------------- K2: sigma -> softmax -> fold w_w@attn ----------------
// Grid (B), 256 threads.
__global__ void k2_attn(const float* __restrict__ tt,
                        const float* __restrict__ mu_in,
                        const float* __restrict__ w_w,
                        float* __restrict__ wct)
{
    __shared__ float s_mu[ICn];
    __shared__ float s_sig[ICn][ICn];
    __shared__ float s_attn[ICn][ICn];
    const int b  = blockIdx.x;
    const int tx = threadIdx.x;

    if (tx < ICn) s_mu[tx] = mu_in[b * ICn + tx] * (1.f / Mn);
    __syncthreads();

    for (int p = tx; p < ICn * ICn; p += 256) {
        int i = p >> 5, j = p & 31;
        s_sig[i][j] = (tt[b * ICn * ICn + p] * (1.f / Mn) - s_mu[i] * s_mu[j])
                      * 0.17677669529663687f;  // 1/sqrt(32)
    }
    __syncthreads();

    if (tx < ICn) {
        float mx = -1e30f;
        #pragma unroll
        for (int j = 0; j < ICn; ++j) mx = fmaxf(mx, s_sig[tx][j]);
        float e[ICn];
        float sum = 0.f;
        #pragma unroll
        for (int j = 0; j < ICn; ++j) { e[j] = __expf(s_sig[tx][j] - mx); sum += e[j]; }
        float r = 1.f / sum;
        #pragma unroll
        for (int j = 0; j < ICn; ++j) s_attn[tx][j] = e[j] * r;
    }
    __syncthreads();

    // wct[b][j][c] = sum_i w_w[c][i] * attn[i][j]
    const int c = tx;
    float wr[ICn];
    #pragma unroll
    for (int i = 0; i < ICn; i += 4) {
        float4 v = *(const float4*)(w_w + c * ICn + i);
        wr[i] = v.x; wr[i + 1] = v.y; wr[i + 2] = v.z; wr[i + 3] = v.w;
    }
    for (int j = 0; j < ICn; ++j) {
        float s = 0.f;
        #pragma unroll
        for (int i = 0; i < ICn; ++i) s += wr[i] * s_attn[i][j];
        wct[((size_t)b * ICn + j) * Cn + c] = s;
    }
}

// ---------------- K3: out = Wc @ gx + w_b + x ----------------
// Grid (M/64, B), 256 threads. Block: all 256 channels x 64 pixels.
__global__ __launch_bounds__(256, 4) void k3_out(
    const float* __restrict__ x,
    const float* __restrict__ gx,
    const float* __restrict__ wct,
    const float* __restrict__ w_b,
    float* __restrict__ out)
{
    __shared__ float wc_s[ICn][Cn];   // [j][c]
    __shared__ float gx_s[ICn][64];
    __shared__ float wb_s[Cn];

    const int tx = threadIdx.x;
    const int b  = blockIdx.y;
    const int m0 = blockIdx.x * 64;

    {   // load Wc (32x256 = 8192 floats)
        const float4* src = (const float4*)(wct + (size_t)b * ICn * Cn);
        float4* dst = (float4*)wc_s;
        #pragma unroll
        for (int p = tx; p < ICn * Cn / 4; p += 256) dst[p] = src[p];
    }
    {   // load gx tile 32x64
        int r  = tx >> 3;
        int c8 = (tx & 7) * 8;
        const float* g = gx + ((size_t)b * ICn + r) * Mn + m0 + c8;
        *(float4*)&gx_s[r][c8]     = *(const float4*)g;
        *(float4*)&gx_s[r][c8 + 4] = *(const float4*)(g + 4);
    }
    if (tx < 64) ((float4*)wb_s)[tx] = ((const float4*)w_b)[tx];
    __syncthreads();

    const int mg = tx & 15;   // pixel quad: m = m0 + mg*4
    const int cg = tx >> 4;   // 16 channel-groups x 16 channels
    float acc[16][4] = {};

    #pragma unroll
    for (int j = 0; j < ICn; ++j) {
        float4 g4 = *(const float4*)&gx_s[j][mg * 4];
        #pragma unroll
        for (int cc = 0; cc < 16; ++cc) {
            float w = wc_s[j][cg * 16 + cc];
            acc[cc][0] += w * g4.x;
            acc[cc][1] += w * g4.y;
            acc[cc][2] += w * g4.z;
            acc[cc][3] += w * g4.w;
        }
    }

    const size_t mbase = (size_t)b * Cn * Mn + m0 + mg * 4;
    #pragma unroll
    for (int cc = 0; cc < 16; ++cc) {
        int c = cg * 16 + cc;
        float4 xv = *(const float4*)(x + mbase + (size_t)c * Mn);
        float wb = wb_s[c];
        float4 o;
        o.x = acc[cc][0] + xv.x + wb;
        o.y = acc[cc][1] + xv.y + wb;
        o.z = acc[cc][2] + xv.z + wb;
        o.w = acc[cc][3] + xv.w + wb;
        *(float4*)(out + mbase + (size_t)c * Mn) = o;
    }
}

extern "C" void kernel_launch(void* const* d_in, const int* in_sizes, int n_in,
                              void* d_out, int out_size, void* d_ws, size_t ws_size,
                              hipStream_t stream) {
    const float* x    = (const float*)d_in[0];
    const float* g_w  = (const float*)d_in[1];
    const float* g_b  = (const float*)d_in[2];
    const float* th_w = (const float*)d_in[3];
    const float* th_b = (const float*)d_in[4];
    const float* w_w  = (const float*)d_in[5];
    const float* w_b  = (const float*)d_in[6];
    float* out = (float*)d_out;
    float* ws  = (float*)d_ws;

    float* gx  = ws + OFF_GX;
    float* wt  = ws + OFF_WT;
    float* wct = ws + OFF_WCT;
    float* tt  = ws + OFF_TT;
    float* mu  = ws + OFF_MU;

    // zero the atomic accumulators (tt and mu are contiguous)
    hipMemsetAsync(tt, 0, (size_t)(Bn * ICn * ICn + Bn * ICn) * sizeof(float), stream);

    k0_transpose_w<<<64, 256, 0, stream>>>(g_w, th_w, wt);
    k1_proj<<<dim3(64, Bn), 256, 0, stream>>>(x, wt, g_b, th_b, gx, tt, mu);
    k2_attn<<<Bn, 256, 0, stream>>>(tt, mu, w_w, wct);
    k3_out<<<dim3(Mn / 64, Bn), 256, 0, stream>>>(x, gx, wct, w_b, out);
}

// Round 2
// 560.563 us; speedup vs baseline: 1.0854x; 1.0854x over previous
//
#include <hip/hip_runtime.h>
#include <math.h>

// Problem constants
constexpr int Bn  = 16;
constexpr int Cn  = 256;
constexpr int Mn  = 16384;  // 128*128
constexpr int ICn = 32;

typedef float v4f   __attribute__((ext_vector_type(4)));
typedef short short8 __attribute__((ext_vector_type(8)));

// ---- workspace layout (in floats) ----
constexpr size_t OFF_GX  = 0;                                   // [B][32][M] fp32
constexpr size_t OFF_WBF = OFF_GX  + (size_t)Bn * ICn * Mn;     // 16384 ushort (swizzled bf16 W)
constexpr size_t OFF_WCT = OFF_WBF + 8192;                      // [B][32][256] folded out-weights
constexpr size_t OFF_TT  = OFF_WCT + (size_t)Bn * ICn * Cn;     // [B][32][32] atomic acc
constexpr size_t OFF_MU  = OFF_TT  + (size_t)Bn * ICn * ICn;    // [B][32] atomic acc

__device__ inline unsigned short f2bf(float f) {
    unsigned u = __float_as_uint(f);
    u += 0x7fffu + ((u >> 16) & 1u);   // RNE (inputs finite)
    return (unsigned short)(u >> 16);
}

// ---------------- K0: weights -> bf16, swizzled LDS image ----------------
// Ws[row][slot*8 + (k&7)] where slot = (k>>3) ^ (row&7). Rows: [g_w ; theta_w].
__global__ void k0_prep_w(const float* __restrict__ g_w,
                          const float* __restrict__ th_w,
                          unsigned short* __restrict__ wbf) {
    int idx = blockIdx.x * 256 + threadIdx.x;   // 16384
    int row = idx >> 8, ks = idx & 255;
    int slot = ks >> 3;
    int k = ((slot ^ (row & 7)) << 3) | (ks & 7);
    float v = (row < ICn) ? g_w[row * Cn + k] : th_w[(row - ICn) * Cn + k];
    wbf[idx] = f2bf(v);
}

// ---------------- K1: MFMA projections + covariance stats ----------------
// Grid (M/64, B), 256 threads (4 waves). Wave w owns px [16w,16w+16), all 64 rows.
// mfma_f32_16x16x32_bf16 with m=px, n=row: A = x^T frags loaded DIRECTLY from
// global (coalesced per-quad), B = W frags from swizzled LDS.
__global__ __launch_bounds__(256, 4) void k1_mfma(
    const float* __restrict__ x,
    const unsigned short* __restrict__ wbf,
    const float* __restrict__ g_b,
    const float* __restrict__ theta_b,
    float* __restrict__ gx,
    float* __restrict__ tt,
    float* __restrict__ mu)
{
    __shared__ __align__(16) unsigned short Ws[64 * 256];  // 32 KB, swizzled
    __shared__ __align__(16) unsigned short Ts[32 * 72];   // t tile bf16, pad 72
    __shared__ float mu_s[ICn];

    const int tx   = threadIdx.x;
    const int b    = blockIdx.y;
    const int m0   = blockIdx.x * 64;
    const int lane = tx & 63;
    const int w    = tx >> 6;       // wave 0..3
    const int ln15 = lane & 15;
    const int q    = lane >> 4;     // quad 0..3

    // W: global (K0 image) -> LDS verbatim, 32 KB
    {
        const int4* src = (const int4*)wbf;
        int4* dst = (int4*)Ws;
        #pragma unroll
        for (int i = 0; i < 8; ++i) dst[tx + 256 * i] = src[tx + 256 * i];
    }
    if (tx < ICn) mu_s[tx] = 0.f;
    __syncthreads();

    v4f acc[4];
    #pragma unroll
    for (int nt = 0; nt < 4; ++nt) acc[nt] = (v4f){0.f, 0.f, 0.f, 0.f};

    // A-frag source: lane -> px = m0 + 16w + ln15, k = kc*32 + q*8 + j
    const float* xbase = x + ((size_t)b * Cn + q * 8) * Mn + m0 + w * 16 + ln15;

    float xf[8];
    #pragma unroll
    for (int j = 0; j < 8; ++j) xf[j] = xbase[(size_t)j * Mn];

    #pragma unroll
    for (int kc = 0; kc < 8; ++kc) {
        short8 a;
        #pragma unroll
        for (int j = 0; j < 8; ++j) a[j] = (short)f2bf(xf[j]);
        if (kc < 7) {
            #pragma unroll
            for (int j = 0; j < 8; ++j)
                xf[j] = xbase[(size_t)((kc + 1) * 32 + j) * Mn];
        }
        #pragma unroll
        for (int nt = 0; nt < 4; ++nt) {
            int row  = nt * 16 + ln15;
            int slot = (kc * 4 + q) ^ (row & 7);
            short8 bf = *(const short8*)&Ws[row * 256 + slot * 8];
            acc[nt] = __builtin_amdgcn_mfma_f32_16x16x32_bf16(a, bf, acc[nt], 0, 0, 0);
        }
    }

    // ---- epilogue ----
    // D layout: n(col)=ln15 -> row, m=(q*4+reg) -> px_local = 16w + q*4 + reg.
    // g rows 0..31: bias + scattered dword stores (L2 merges partial lines)
    #pragma unroll
    for (int nt = 0; nt < 2; ++nt) {
        int row = nt * 16 + ln15;
        float bb = g_b[row];
        float* gp = gx + ((size_t)b * ICn + row) * Mn + m0 + w * 16 + q * 4;
        #pragma unroll
        for (int r = 0; r < 4; ++r) gp[r] = acc[nt][r] + bb;
    }

    // theta rows 0..31: bias -> Ts (bf16) + mu partials
    #pragma unroll
    for (int nt = 2; nt < 4; ++nt) {
        int tr = (nt - 2) * 16 + ln15;
        float bb = theta_b[tr];
        float s = 0.f;
        #pragma unroll
        for (int r = 0; r < 4; ++r) {
            float tv = acc[nt][r] + bb;
            Ts[tr * 72 + w * 16 + q * 4 + r] = f2bf(tv);
            s += tv;
        }
        s += __shfl_xor(s, 16);
        s += __shfl_xor(s, 32);
        if (q == 0) atomicAdd(&mu_s[tr], s);
    }
    __syncthreads();

    // tt += T T^T over this block's 64 px (MFMA, both frags same pattern)
    {
        int i0 = (w & 1) * 16, j0 = (w >> 1) * 16;
        v4f at = (v4f){0.f, 0.f, 0.f, 0.f};
        #pragma unroll
        for (int pc = 0; pc < 2; ++pc) {
            short8 A  = *(const short8*)&Ts[(i0 + ln15) * 72 + pc * 32 + q * 8];
            short8 Bv = *(const short8*)&Ts[(j0 + ln15) * 72 + pc * 32 + q * 8];
            at = __builtin_amdgcn_mfma_f32_16x16x32_bf16(A, Bv, at, 0, 0, 0);
        }
        float* ttb = tt + (size_t)b * ICn * ICn;
        #pragma unroll
        for (int r = 0; r < 4; ++r)
            atomicAdd(&ttb[(i0 + q * 4 + r) * ICn + j0 + ln15], at[r]);
    }
    if (tx < ICn) atomicAdd(&mu[b * ICn + tx], mu_s[tx]);
}

// ---------------- K2: sigma -> softmax -> fold w_w@attn ----------------
__global__ void k2_attn(const float* __restrict__ tt,
                        const float* __restrict__ mu_in,
                        const float* __restrict__ w_w,
                        float* __restrict__ wct)
{
    __shared__ float s_mu[ICn];
    __shared__ float s_sig[ICn][ICn];
    __shared__ float s_attn[ICn][ICn];
    const int b  = blockIdx.x;
    const int tx = threadIdx.x;

    if (tx < ICn) s_mu[tx] = mu_in[b * ICn + tx] * (1.f / Mn);
    __syncthreads();

    for (int p = tx; p < ICn * ICn; p += 256) {
        int i = p >> 5, j = p & 31;
        s_sig[i][j] = (tt[b * ICn * ICn + p] * (1.f / Mn) - s_mu[i] * s_mu[j])
                      * 0.17677669529663687f;  // 1/sqrt(32)
    }
    __syncthreads();

    if (tx < ICn) {
        float mx = -1e30f;
        #pragma unroll
        for (int j = 0; j < ICn; ++j) mx = fmaxf(mx, s_sig[tx][j]);
        float e[ICn];
        float sum = 0.f;
        #pragma unroll
        for (int j = 0; j < ICn; ++j) { e[j] = __expf(s_sig[tx][j] - mx); sum += e[j]; }
        float r = 1.f / sum;
        #pragma unroll
        for (int j = 0; j < ICn; ++j) s_attn[tx][j] = e[j] * r;
    }
    __syncthreads();

    const int c = tx;
    float wr[ICn];
    #pragma unroll
    for (int i = 0; i < ICn; i += 4) {
        float4 v = *(const float4*)(w_w + c * ICn + i);
        wr[i] = v.x; wr[i + 1] = v.y; wr[i + 2] = v.z; wr[i + 3] = v.w;
    }
    for (int j = 0; j < ICn; ++j) {
        float s = 0.f;
        #pragma unroll
        for (int i = 0; i < ICn; ++i) s += wr[i] * s_attn[i][j];
        wct[((size_t)b * ICn + j) * Cn + c] = s;
    }
}

// ---------------- K3: out = Wc @ gx + w_b + x ----------------
__global__ __launch_bounds__(256, 4) void k3_out(
    const float* __restrict__ x,
    const float* __restrict__ gx,
    const float* __restrict__ wct,
    const float* __restrict__ w_b,
    float* __restrict__ out)
{
    __shared__ float wc_s[ICn][Cn];
    __shared__ float gx_s[ICn][64];
    __shared__ float wb_s[Cn];

    const int tx = threadIdx.x;
    const int b  = blockIdx.y;
    const int m0 = blockIdx.x * 64;

    {
        const float4* src = (const float4*)(wct + (size_t)b * ICn * Cn);
        float4* dst = (float4*)wc_s;
        #pragma unroll
        for (int p = tx; p < ICn * Cn / 4; p += 256) dst[p] = src[p];
    }
    {
        int r  = tx >> 3;
        int c8 = (tx & 7) * 8;
        const float* g = gx + ((size_t)b * ICn + r) * Mn + m0 + c8;
        *(float4*)&gx_s[r][c8]     = *(const float4*)g;
        *(float4*)&gx_s[r][c8 + 4] = *(const float4*)(g + 4);
    }
    if (tx < 64) ((float4*)wb_s)[tx] = ((const float4*)w_b)[tx];
    __syncthreads();

    const int mg = tx & 15;
    const int cg = tx >> 4;
    float acc[16][4] = {};

    #pragma unroll
    for (int j = 0; j < ICn; ++j) {
        float4 g4 = *(const float4*)&gx_s[j][mg * 4];
        #pragma unroll
        for (int cc = 0; cc < 16; ++cc) {
            float w = wc_s[j][cg * 16 + cc];
            acc[cc][0] += w * g4.x;
            acc[cc][1] += w * g4.y;
            acc[cc][2] += w * g4.z;
            acc[cc][3] += w * g4.w;
        }
    }

    const size_t mbase = (size_t)b * Cn * Mn + m0 + mg * 4;
    #pragma unroll
    for (int cc = 0; cc < 16; ++cc) {
        int c = cg * 16 + cc;
        float4 xv = *(const float4*)(x + mbase + (size_t)c * Mn);
        float wb = wb_s[c];
        float4 o;
        o.x = acc[cc][0] + xv.x + wb;
        o.y = acc[cc][1] + xv.y + wb;
        o.z = acc[cc][2] + xv.z + wb;
        o.w = acc[cc][3] + xv.w + wb;
        *(float4*)(out + mbase + (size_t)c * Mn) = o;
    }
}

extern "C" void kernel_launch(void* const* d_in, const int* in_sizes, int n_in,
                              void* d_out, int out_size, void* d_ws, size_t ws_size,
                              hipStream_t stream) {
    const float* x    = (const float*)d_in[0];
    const float* g_w  = (const float*)d_in[1];
    const float* g_b  = (const float*)d_in[2];
    const float* th_w = (const float*)d_in[3];
    const float* th_b = (const float*)d_in[4];
    const float* w_w  = (const float*)d_in[5];
    const float* w_b  = (const float*)d_in[6];
    float* out = (float*)d_out;
    float* ws  = (float*)d_ws;

    float* gx            = ws + OFF_GX;
    unsigned short* wbf  = (unsigned short*)(ws + OFF_WBF);
    float* wct           = ws + OFF_WCT;
    float* tt            = ws + OFF_TT;
    float* mu            = ws + OFF_MU;

    // zero atomic accumulators (tt and mu contiguous)
    hipMemsetAsync(tt, 0, (size_t)(Bn * ICn * ICn + Bn * ICn) * sizeof(float), stream);

    k0_prep_w<<<64, 256, 0, stream>>>(g_w, th_w, wbf);
    k1_mfma<<<dim3(Mn / 64, Bn), 256, 0, stream>>>(x, wbf, g_b, th_b, gx, tt, mu);
    k2_attn<<<Bn, 256, 0, stream>>>(tt, mu, w_w, wct);
    k3_out<<<dim3(Mn / 64, Bn), 256, 0, stream>>>(x, gx, wct, w_b, out);
}